// Round 13
// baseline (12080.082 us; speedup 1.0000x reference)
//
#include <hip/hip_runtime.h>

#define B_   16
#define T_   1600
#define D_   512
#define U_   1024
#define G_   4096           // 4*U
#define NWG  128            // each WG owns 8 fwd units AND 8 bwd units
#define TPB  256            // 4 waves = 1/SIMD -> 512 VGPR budget
#define KTOT 1536           // D + U
#define APAD 1544           // weight staging pad (ushort elems)
#define ROWB (APAD*2)
#define X16OFF (1 << 18)    // 4 x 64KB tagged h images fill [0, 256KB)

typedef __attribute__((ext_vector_type(8))) __bf16 bf16x8;
typedef __attribute__((ext_vector_type(4))) float  f32x4;
typedef __attribute__((ext_vector_type(2))) float  f32x2;
typedef __attribute__((ext_vector_type(4))) unsigned int uint4v;
typedef __attribute__((ext_vector_type(8))) unsigned short us8v;
typedef unsigned long long u64;
typedef unsigned int u32;

__device__ __forceinline__ unsigned short f2bf(float f) {
  unsigned u = __builtin_bit_cast(unsigned, f);
  u += 0x7FFFu + ((u >> 16) & 1u);          // RNE
  return (unsigned short)(u >> 16);
}
__device__ __forceinline__ bf16x8 cvt8(const float4 a, const float4 b) {
  us8v r;
  r[0]=f2bf(a.x); r[1]=f2bf(a.y); r[2]=f2bf(a.z); r[3]=f2bf(a.w);
  r[4]=f2bf(b.x); r[5]=f2bf(b.y); r[6]=f2bf(b.z); r[7]=f2bf(b.w);
  return __builtin_bit_cast(bf16x8, r);
}
__device__ __forceinline__ float sigm(float x){ return 1.f / (1.f + __expf(-x)); }
__device__ __forceinline__ float tanh_(float x){ return 1.f - 2.f / (__expf(2.f*x) + 1.f); }

// one-time x fp32 -> bf16
extern "C" __global__ void __launch_bounds__(256)
xcvt_kernel(const float* __restrict__ xin, unsigned short* __restrict__ x16) {
  const size_t i = ((size_t)blockIdx.x*256 + threadIdx.x) * 8;
  float4 a = *(const float4*)(xin + i);
  float4 b = *(const float4*)(xin + i + 4);
  *(us8v*)(x16 + i) = __builtin_bit_cast(us8v, cvt8(a, b));
}

extern "C" __global__ void __launch_bounds__(TPB, 1)
bilstm_kernel(const float* __restrict__ x, const int* __restrict__ xlen,
              const float* __restrict__ kf, const float* __restrict__ rkf, const float* __restrict__ bf_,
              const float* __restrict__ kb, const float* __restrict__ rkb, const float* __restrict__ bb_,
              float* __restrict__ out, u32* __restrict__ hbuf32,
              const unsigned short* __restrict__ x16, int use16)
{
  extern __shared__ char smem[];

  const int tid  = threadIdx.x;
  const int slot = blockIdx.x;        // 0..127
  const int u0   = slot << 3;         // 8 units per direction

  if (slot == 0 && tid < B_)
    out[(size_t)B_*T_*2*U_ + tid] = (float)xlen[tid];

  const int w = tid >> 6, l = tid & 63;
  const int ntile = w & 1, khalf = w >> 1;

  // ---- one-time: stage + extract weights for BOTH directions into VGPRs ----
  bf16x8 wxf[8], whf[16], wxb[8], whb[16];
  {
    char* Wb = smem;
    // fwd
    for (int i = tid; i < KTOT*32; i += TPB) {
      int k = i >> 5, c = i & 31;
      int gc = ((c >> 3) << 10) + u0 + (c & 7);
      float wv = (k < D_) ? kf[(size_t)k*G_ + gc] : rkf[(size_t)(k-D_)*G_ + gc];
      *(unsigned short*)(Wb + c*ROWB + (k << 1)) = f2bf(wv);
    }
    __syncthreads();
    {
      const char* Brow = smem + (ntile*16 + (l & 15))*ROWB + ((l >> 4) << 4);
      #pragma unroll
      for (int i = 0; i < 8; ++i)  wxf[i] = *(const bf16x8*)(Brow + ((khalf*8 + i) << 6));
      #pragma unroll
      for (int i = 0; i < 16; ++i) whf[i] = *(const bf16x8*)(Brow + ((16 + khalf*16 + i) << 6));
    }
    __syncthreads();
    // bwd (reuse staging buffer)
    for (int i = tid; i < KTOT*32; i += TPB) {
      int k = i >> 5, c = i & 31;
      int gc = ((c >> 3) << 10) + u0 + (c & 7);
      float wv = (k < D_) ? kb[(size_t)k*G_ + gc] : rkb[(size_t)(k-D_)*G_ + gc];
      *(unsigned short*)(Wb + c*ROWB + (k << 1)) = f2bf(wv);
    }
    __syncthreads();
    {
      const char* Brow = smem + (ntile*16 + (l & 15))*ROWB + ((l >> 4) << 4);
      #pragma unroll
      for (int i = 0; i < 8; ++i)  wxb[i] = *(const bf16x8*)(Brow + ((khalf*8 + i) << 6));
      #pragma unroll
      for (int i = 0; i < 16; ++i) whb[i] = *(const bf16x8*)(Brow + ((16 + khalf*16 + i) << 6));
    }
    __syncthreads();   // staging dead; reuse: gates @0 (4KB), h-stage @4096 (32KB)
  }

  float* gates = (float*)smem;            // [2 khalf][16 b][32 col]
  char*  hst   = smem + 4096;             // [16 b][2048 B] XOR-swizzled bf16 h
  float* gp    = gates + khalf*512;
  const int drow0 = (l >> 4) << 2, dcol = ntile*16 + (l & 15);

  // epilogue-lane state (wave 0): 2 units per lane, both directions
  const int eb = tid >> 2, eup = (tid & 3) << 1;
  float bfr[8] = {0,0,0,0,0,0,0,0}, bbr[8] = {0,0,0,0,0,0,0,0};
  float cf0=0, cf1=0, cb0=0, cb1=0;
  if (tid < 64) {
    #pragma unroll
    for (int g = 0; g < 4; ++g) {
      bfr[2*g]   = bf_[(g << 10) + u0 + eup];
      bfr[2*g+1] = bf_[(g << 10) + u0 + eup + 1];
      bbr[2*g]   = bb_[(g << 10) + u0 + eup];
      bbr[2*g+1] = bb_[(g << 10) + u0 + eup + 1];
    }
  }

  // per-lane x bases
  const float* xbase = x + (size_t)(l & 15)*T_*D_ + khalf*256 + ((l >> 4) << 3);
  const unsigned short* x16b = x16 + (size_t)(l & 15)*T_*D_ + khalf*256 + ((l >> 4) << 3);

  const char* hrow  = hst + (l & 15)*2048;
  const int   kbase = (khalf*512 + ((l >> 4) << 3)) << 1;
  const int   swz   = ((l & 15) & 7) << 4;
  const unsigned off0 = (unsigned)tid * 16;

#define XPROJ(nacc, wxA, tgi)                                                            \
  do {                                                                                   \
    if (use16) {                                                                         \
      const unsigned short* xA = x16b + (size_t)(tgi) * D_;                              \
      _Pragma("unroll")                                                                  \
      for (int i = 0; i < 8; ++i)                                                        \
        nacc = __builtin_amdgcn_mfma_f32_16x16x32_bf16(*(const bf16x8*)(xA + i*32),      \
                                                       wxA[i], nacc, 0, 0, 0);           \
    } else {                                                                             \
      const float* xA = xbase + (size_t)(tgi) * D_;                                      \
      _Pragma("unroll")                                                                  \
      for (int i = 0; i < 8; ++i) {                                                      \
        float4 lo = *(const float4*)(xA + i*32);                                         \
        float4 hi = *(const float4*)(xA + i*32 + 4);                                     \
        nacc = __builtin_amdgcn_mfma_f32_16x16x32_bf16(cvt8(lo, hi), wxA[i], nacc,       \
                                                       0, 0, 0);                         \
      }                                                                                  \
    }                                                                                    \
  } while (0)

  // prologue: x-projection at t=0 for both directions
  f32x4 accf = {0.f,0.f,0.f,0.f}, accb = {0.f,0.f,0.f,0.f};
  XPROJ(accf, wxf, 0);
  XPROJ(accb, wxb, T_ - 1);

#define SECTION(DIR, acc, whA, wxA, biasA, cc0, cc1, tg_cur, tg_next)                    \
  do {                                                                                   \
    if (t > 0) {                                                                         \
      const u32* hb = hbuf32 + (size_t)((t & 1)*2 + DIR) * 16384;                        \
      const unsigned tagv = (unsigned)t << 16;                                           \
      uint4v hv[16];                                                                     \
      long long guard = 0;                                                               \
      for (;;) {                                                                         \
        _Pragma("unroll")                                                                \
        for (int j = 0; j < 16; ++j)                                                     \
          asm volatile("global_load_dwordx4 %0, %1, %2 sc0 sc1"                          \
                       : "=v"(hv[j]) : "v"(off0 + (unsigned)(j*4096)), "s"(hb));         \
        asm volatile("s_waitcnt vmcnt(0)" ::: "memory");                                 \
        __builtin_amdgcn_sched_barrier(0);                                               \
        unsigned bad = 0;                                                                \
        _Pragma("unroll")                                                                \
        for (int j = 0; j < 16; ++j)                                                     \
          bad |= (hv[j][0] ^ tagv) | (hv[j][2] ^ tagv);                                  \
        if (!(bad & 0xFFFF0000u)) break;                                                 \
        __builtin_amdgcn_s_sleep(1);                                                     \
        if (++guard > (1LL << 22)) break;                                                \
      }                                                                                  \
      _Pragma("unroll")                                                                  \
      for (int j = 0; j < 16; ++j) {                                                     \
        u32 lo = __builtin_amdgcn_perm(hv[j][1], hv[j][0], 0x05040100u);                 \
        u32 hi = __builtin_amdgcn_perm(hv[j][3], hv[j][2], 0x05040100u);                 \
        *(u64*)(hst + j*2048 + ((tid << 3) ^ ((j & 7) << 4))) = ((u64)hi << 32) | lo;    \
      }                                                                                  \
    }                                                                                    \
    __syncthreads();  /* SA: h staged; gates/hst free from prior section */              \
    if (t > 0) {                                                                         \
      f32x4 a2 = {0.f,0.f,0.f,0.f};                                                      \
      _Pragma("unroll")                                                                  \
      for (int i = 0; i < 16; i += 2) {                                                  \
        bf16x8 a0 = *(const bf16x8*)(hrow + ((kbase + i*64)     ^ swz));                 \
        bf16x8 a1 = *(const bf16x8*)(hrow + ((kbase + (i+1)*64) ^ swz));                 \
        acc = __builtin_amdgcn_mfma_f32_16x16x32_bf16(a0, whA[i],   acc, 0, 0, 0);       \
        a2  = __builtin_amdgcn_mfma_f32_16x16x32_bf16(a1, whA[i+1], a2,  0, 0, 0);       \
      }                                                                                  \
      acc[0]+=a2[0]; acc[1]+=a2[1]; acc[2]+=a2[2]; acc[3]+=a2[3];                        \
    }                                                                                    \
    _Pragma("unroll")                                                                    \
    for (int j = 0; j < 4; ++j) gp[(drow0 + j)*32 + dcol] = acc[j];                      \
    __syncthreads();  /* SB: gates ready; hst reads done */                              \
    if (tid < 64) {                                                                      \
      const float* g0 = gates + eb*32 + eup;                                             \
      float gi0 = g0[0]  + g0[512] + biasA[0], gi1 = g0[1]  + g0[513] + biasA[1];        \
      float gf0 = g0[8]  + g0[520] + biasA[2], gf1 = g0[9]  + g0[521] + biasA[3];        \
      float gz0 = g0[16] + g0[528] + biasA[4], gz1 = g0[17] + g0[529] + biasA[5];        \
      float go0 = g0[24] + g0[536] + biasA[6], go1 = g0[25] + g0[537] + biasA[7];        \
      cc0 = sigm(gf0)*cc0 + sigm(gi0)*tanh_(gz0);                                        \
      cc1 = sigm(gf1)*cc1 + sigm(gi1)*tanh_(gz1);                                        \
      float h0 = sigm(go0)*tanh_(cc0);                                                   \
      float h1 = sigm(go1)*tanh_(cc1);                                                   \
      const unsigned tagw = (unsigned)(t + 1) << 16;                                     \
      u32 w0 = (u32)f2bf(h0) | tagw;                                                     \
      u32 w1 = (u32)f2bf(h1) | tagw;                                                     \
      u32* hdst = hbuf32 + (size_t)(((t & 1) ^ 1)*2 + DIR)*16384 + (eb << 10) + u0 + eup;\
      __hip_atomic_store((u64*)hdst, ((u64)w1 << 32) | w0, __ATOMIC_RELAXED,             \
                         __HIP_MEMORY_SCOPE_AGENT);                                      \
      f32x2 ho; ho.x = h0; ho.y = h1;                                                    \
      *(f32x2*)(out + ((size_t)eb*T_ + (tg_cur))*(2*U_) + (DIR << 10) + u0 + eup) = ho;  \
    }                                                                                    \
    if (t + 1 < T_) {                                                                    \
      f32x4 nacc = {0.f,0.f,0.f,0.f};                                                    \
      XPROJ(nacc, wxA, tg_next);                                                         \
      acc = nacc;                                                                        \
    }                                                                                    \
  } while (0)

  for (int t = 0; t < T_; ++t) {
    SECTION(0, accf, whf, wxf, bfr, cf0, cf1, t,          t + 1);
    SECTION(1, accb, whb, wxb, bbr, cb0, cb1, T_ - 1 - t, T_ - 2 - t);
  }
}

extern "C" void kernel_launch(void* const* d_in, const int* in_sizes, int n_in,
                              void* d_out, int out_size, void* d_ws, size_t ws_size,
                              hipStream_t stream) {
  const float* x   = (const float*)d_in[0];
  const int*   xl  = (const int*)d_in[1];
  const float* kf  = (const float*)d_in[2];
  const float* rkf = (const float*)d_in[3];
  const float* bf_ = (const float*)d_in[4];
  const float* kb  = (const float*)d_in[5];
  const float* rkb = (const float*)d_in[6];
  const float* bb_ = (const float*)d_in[7];
  float* out = (float*)d_out;

  u32* hbuf32 = (u32*)d_ws;                                       // 4 x 64KB tagged h images
  unsigned short* x16 = (unsigned short*)((char*)d_ws + X16OFF);  // 26.2 MB bf16 x

  const size_t need = (size_t)X16OFF + (size_t)B_*T_*D_*2;
  const int use16 = (ws_size >= need) ? 1 : 0;

  (void)hipMemsetAsync(d_ws, 0, X16OFF, stream);    // zero all tags (graph-safe)
  if (use16)
    xcvt_kernel<<<6400, 256, 0, stream>>>(x, x16);

  const size_t smem = 32*(size_t)ROWB;   // 98,816 B (weight staging); runtime uses 36,864 B
  bilstm_kernel<<<NWG, TPB, smem, stream>>>(x, xl, kf, rkf, bf_, kb, rkb, bb_,
                                            out, hbuf32, x16, use16);
}